// Round 5
// baseline (166.979 us; speedup 1.0000x reference)
//
#include <hip/hip_runtime.h>

// ---------------------------------------------------------------------------
// FixedRateVectorQuantizer (N=131072, D=128, P=512), Mahalanobis VQ.
// Out: [N*D quantized][commit][cb_loss][N idx-as-float]  (fp32)
//
// Whitened: S = inv(cov) ~ L L^T, L = sqrt(c)[(3/2)I - (c/2)cov], c = 128/tr
//   scores_p = x.(S c_p) = x.w_p with W = C S = Ch L  (Ch = C L, L symm)
//   argmin_p d = argmax_p packed(x.w_p + 1024 - |chat_p|^2/2, tag=511-idx)
//   xSx = sum((X Sh) .* X), Sh = L L
//   min_p d = xSx - 2*(max_val - 1024);  M = mean_r min d;  commit = 0.1 M
//   cb_loss = M - 2e5 * entropy(counts)
// 4 dispatches: k_prep1 (64), k_prep23 (40), k_main (256x1024), k_final (1).
//
// R5 (W fully LDS-resident, barrier-free code loop):
//   - k_main: 256 blocks x 1024 threads (1 block/CU, 16 waves, 4 waves/SIMD).
//     W (128 KB) staged ONCE into LDS via global_load_lds; the 32-tile argmax
//     loop is pure LDS+MFMA: no barriers, no staging, no global deps.
//   - A-fragments straight from global X (f32->f16 in reg); no Xs LDS.
//   - xSx via 8 Sh-tile iters with B-frags from global L2, overlapping the
//     one-time W stage (single __syncthreads drains it).
//   - prep2+prep3 fused into k_prep23 (Ch+cq, barrier, W=Ch*L; Sh blocks).
// ---------------------------------------------------------------------------

typedef _Float16 half8 __attribute__((ext_vector_type(8)));
typedef float floatx4 __attribute__((ext_vector_type(4)));

#define NROWS 131072
#define DIM 128
#define NCODE 512
#define ND 16777216

// ---- workspace layout (bytes) ----
#define WS_LH    0        // 128x128 f16 (L, symmetric), XOR-swizzled rows
#define WS_CH    32768    // 512x128 f16 (C*L), XOR-swizzled rows
#define WS_W     163840   // 512x128 f16 (C*S = Ch*L), XOR-swizzled rows
#define WS_SH    294912   // 128x128 f16 (S = L*L), XOR-swizzled rows
#define WS_CQ    327680   // 512 f32  (1024 - 0.5|chat|^2)
#define WS_CNT   329728   // 8 x 512 u32 (XCD replicas, zeroed by k_prep1)
#define WS_SUMS  346112   // 8 x 32 f32  (XCD replicas, zeroed by k_prep1)

#define MFMA16(A, B, C) __builtin_amdgcn_mfma_f32_16x16x32_f16(A, B, C, 0, 0, 0)

// byte offset of element (row, colh[halfwords]) in a 256B-row f16 matrix,
// with XOR swizzle spreading the 16 rows of a tile across banks.
__device__ __forceinline__ int moff(int row, int colh) {
  return row * 256 + ((((row & 7) << 4) ^ (colh * 2)));
}

// ---------------- prep1: mu, trace, L rows (f16); zero counters ----------
// 64 blocks x 256. Block b: L rows 2b, 2b+1 (Gram trick, no cov materialized).
__global__ __launch_bounds__(256) void k_prep1(
    const float* __restrict__ cb, _Float16* __restrict__ Lh,
    unsigned* __restrict__ cnt, float* __restrict__ sums) {
  __shared__ float mu[128];
  __shared__ float red[256];
  __shared__ float colI[2][512];
  __shared__ float csh[2];

  const int t = threadIdx.x, b = blockIdx.x;
  const int j = t & 127, h = t >> 7;

  // zero atomic replicas for k_main
  if (b < 8) {
    cnt[b * 512 + t] = 0u;
    cnt[b * 512 + 256 + t] = 0u;
  }
  if (b == 8) sums[t] = 0.f;  // only t<256 exists; sums is 256 floats

  // column means + column sumsq (for trace)
  float sm = 0.f, sf = 0.f;
  for (int p = 0; p < 256; ++p) {
    float v = cb[(h * 256 + p) * DIM + j];
    sm += v;
    sf += v * v;
  }
  red[t] = sm;
  // stage columns 2b, 2b+1
  for (int k = t; k < 1024; k += 256)
    colI[k >> 9][k & 511] = cb[(k & 511) * DIM + 2 * b + (k >> 9)];
  __syncthreads();
  if (t < 128) mu[t] = (red[t] + red[t + 128]) * (1.f / 512.f);
  __syncthreads();
  red[t] = sf - ((t < 128) ? 512.f * mu[t] * mu[t] : 0.f);
  __syncthreads();
  for (int k = 128; k > 0; k >>= 1) {
    if (t < k) red[t] += red[t + k];
    __syncthreads();
  }
  if (t == 0) {
    float tr = red[0] * (1.f / 511.f) + 0.128f;  // + 128*1e-3 ridge
    csh[0] = 128.f / tr;
    csh[1] = sqrtf(128.f / tr);
  }
  __syncthreads();
  const float c = csh[0], rc = csh[1];

  // L row i = 2b+h:  L = rc*[ (1.5 - 5e-4c) I - (c/1022)(G - 512 mu mu^T) ]
  const int i = 2 * b + h;
  float g = 0.f;
  for (int q = 0; q < 512; ++q) g += colI[h][q] * cb[q * DIM + j];
  float lv = rc * (((i == j) ? (1.5f - 5e-4f * c) : 0.f) -
                   (c / 1022.f) * (g - 512.f * mu[i] * mu[j]));
  *(_Float16*)((char*)Lh + moff(i, j)) = (_Float16)lv;  // swizzled store
}

// ---------------- prep23: Ch = C*L + cq; then W = Ch*L; Sh = L*L ----------
// 40 blocks x 256. Blocks 0..31: codes p0=16b (phase1 Ch+cq, phase2 W).
// Blocks 32..39: Sh rows 16(b-32) (no dependency on Ch).
__global__ __launch_bounds__(256) void k_prep23(
    const float* __restrict__ cb, const _Float16* __restrict__ Lh,
    _Float16* __restrict__ Ch, _Float16* __restrict__ W,
    _Float16* __restrict__ Sh, float* __restrict__ cqb) {
  __shared__ float cqpart[16][4];
  const int t = threadIdx.x;
  const int w = t >> 6, lane = t & 63, quad = lane >> 4, l16 = lane & 15;

  if (blockIdx.x >= 32) {
    // ---- Sh = L * L (rows p0..p0+15) ----
    const int p0 = (blockIdx.x - 32) * 16;
    half8 a[4];
#pragma unroll
    for (int ci = 0; ci < 4; ++ci)
      a[ci] = *(const half8*)((const char*)Lh + moff(p0 + l16, ci * 32 + quad * 8));
#pragma unroll
    for (int t2 = 0; t2 < 2; ++t2) {
      const int tile = w * 2 + t2;
      floatx4 s = {0.f, 0.f, 0.f, 0.f};
#pragma unroll
      for (int ci = 0; ci < 4; ++ci) {
        half8 bb = *(const half8*)((const char*)Lh +
                                   moff(tile * 16 + l16, ci * 32 + quad * 8));
        s = MFMA16(a[ci], bb, s);
      }
#pragma unroll
      for (int r = 0; r < 4; ++r)
        *(_Float16*)((char*)Sh + moff(p0 + quad * 4 + r, tile * 16 + l16)) =
            (_Float16)s[r];
    }
    return;
  }

  const int p0 = blockIdx.x * 16;

  // ---- phase 1: Ch rows p0..p0+15 (A = cb f32->f16, B = Lh), cq ----
  half8 a[4];
#pragma unroll
  for (int ci = 0; ci < 4; ++ci) {
    const float4* v = (const float4*)(cb + (p0 + l16) * DIM + ci * 32 + quad * 8);
    float4 v0 = v[0], v1 = v[1];
    half8 hh;
    hh[0] = (_Float16)v0.x; hh[1] = (_Float16)v0.y;
    hh[2] = (_Float16)v0.z; hh[3] = (_Float16)v0.w;
    hh[4] = (_Float16)v1.x; hh[5] = (_Float16)v1.y;
    hh[6] = (_Float16)v1.z; hh[7] = (_Float16)v1.w;
    a[ci] = hh;
  }
  float sq[4] = {0.f, 0.f, 0.f, 0.f};
#pragma unroll
  for (int t2 = 0; t2 < 2; ++t2) {
    const int tile = w * 2 + t2;
    floatx4 s = {0.f, 0.f, 0.f, 0.f};
#pragma unroll
    for (int ci = 0; ci < 4; ++ci) {
      half8 bb = *(const half8*)((const char*)Lh +
                                 moff(tile * 16 + l16, ci * 32 + quad * 8));
      s = MFMA16(a[ci], bb, s);
    }
#pragma unroll
    for (int r = 0; r < 4; ++r) {
      *(_Float16*)((char*)Ch + moff(p0 + quad * 4 + r, tile * 16 + l16)) =
          (_Float16)s[r];
      sq[r] += s[r] * s[r];
    }
  }
#pragma unroll
  for (int r = 0; r < 4; ++r) {
    float v = sq[r];
    v += __shfl_xor(v, 1); v += __shfl_xor(v, 2);
    v += __shfl_xor(v, 4); v += __shfl_xor(v, 8);
    sq[r] = v;
  }
  if (l16 == 0)
#pragma unroll
    for (int r = 0; r < 4; ++r) cqpart[quad * 4 + r][w] = sq[r];
  __syncthreads();  // Ch stores drained (vmcnt0) -> L2-visible; cqpart ready
  if (t < 16)
    cqb[p0 + t] = 1024.f - 0.5f * (cqpart[t][0] + cqpart[t][1] +
                                   cqpart[t][2] + cqpart[t][3]);

  // ---- phase 2: W rows p0..p0+15 = Ch rows * L (read own Ch back) ----
  half8 a2[4];
#pragma unroll
  for (int ci = 0; ci < 4; ++ci)
    a2[ci] = *(const half8*)((const char*)Ch + moff(p0 + l16, ci * 32 + quad * 8));
#pragma unroll
  for (int t2 = 0; t2 < 2; ++t2) {
    const int tile = w * 2 + t2;
    floatx4 s = {0.f, 0.f, 0.f, 0.f};
#pragma unroll
    for (int ci = 0; ci < 4; ++ci) {
      half8 bb = *(const half8*)((const char*)Lh +
                                 moff(tile * 16 + l16, ci * 32 + quad * 8));
      s = MFMA16(a2[ci], bb, s);
    }
#pragma unroll
    for (int r = 0; r < 4; ++r)
      *(_Float16*)((char*)W + moff(p0 + quad * 4 + r, tile * 16 + l16)) =
          (_Float16)s[r];
  }
}

// ---------------- main fused kernel ----------------
// 256 blocks x 1024 threads (1 block/CU; 16 waves; wave owns 32 rows).
// W (128 KB) fully LDS-resident; argmax loop is barrier-free LDS+MFMA.
__global__ __launch_bounds__(1024, 4) void k_main(
    const float* __restrict__ X, const float* __restrict__ cb,
    const _Float16* __restrict__ Sh, const _Float16* __restrict__ W,
    const float* __restrict__ cqb, float* __restrict__ out,
    unsigned* __restrict__ cnt, float* __restrict__ sums) {
  __shared__ __align__(16) char Ws[131072];  // full W, XOR-swizzled rows

  const int tid = threadIdx.x;
  const int w = tid >> 6, lane = tid & 63;
  const int quad = lane >> 4, l16 = lane & 15;
  const int R0 = blockIdx.x * 512 + w * 32;  // this wave's 32 rows
  const int rep = blockIdx.x & 7;

  // ---- A fragments straight from global X (f32 -> f16 in registers) ----
  half8 a0[4], a1[4];
#pragma unroll
  for (int ci = 0; ci < 4; ++ci) {
    const float4* p0 = (const float4*)(X + (size_t)(R0 + l16) * DIM + ci * 32 + quad * 8);
    float4 u0 = p0[0], u1 = p0[1];
    half8 h;
    h[0] = (_Float16)u0.x; h[1] = (_Float16)u0.y;
    h[2] = (_Float16)u0.z; h[3] = (_Float16)u0.w;
    h[4] = (_Float16)u1.x; h[5] = (_Float16)u1.y;
    h[6] = (_Float16)u1.z; h[7] = (_Float16)u1.w;
    a0[ci] = h;
    const float4* p1 = (const float4*)(X + (size_t)(R0 + 16 + l16) * DIM + ci * 32 + quad * 8);
    float4 w0 = p1[0], w1 = p1[1];
    h[0] = (_Float16)w0.x; h[1] = (_Float16)w0.y;
    h[2] = (_Float16)w0.z; h[3] = (_Float16)w0.w;
    h[4] = (_Float16)w1.x; h[5] = (_Float16)w1.y;
    h[6] = (_Float16)w1.z; h[7] = (_Float16)w1.w;
    a1[ci] = h;
  }

  // ---- one-time stage: W 128KB -> LDS (16 waves x 8 slabs x 1KB) ----
  const char* WB = (const char*)W;
#pragma unroll
  for (int i = 0; i < 8; ++i)
    __builtin_amdgcn_global_load_lds(
        (const __attribute__((address_space(1))) void*)(WB + i * 16384 + w * 1024 + lane * 16),
        (__attribute__((address_space(3))) void*)(Ws + i * 16384 + w * 1024),
        16, 0, 0);

  // ---- xSx: 8 Sh tiles, B-frags from global L2 (overlaps the W stage) ----
  float y2 = 0.f;
  const char* ShB = (const char*)Sh;
  for (int v = 0; v < 8; ++v) {
    half8 bb[4];
#pragma unroll
    for (int ci = 0; ci < 4; ++ci)
      bb[ci] = *(const half8*)(ShB + moff(v * 16 + l16, ci * 32 + quad * 8));
    floatx4 s0a = {0.f, 0.f, 0.f, 0.f}, s0b = {0.f, 0.f, 0.f, 0.f};
    floatx4 s1a = {0.f, 0.f, 0.f, 0.f}, s1b = {0.f, 0.f, 0.f, 0.f};
    s0a = MFMA16(a0[0], bb[0], s0a); s0b = MFMA16(a0[1], bb[1], s0b);
    s1a = MFMA16(a1[0], bb[0], s1a); s1b = MFMA16(a1[1], bb[1], s1b);
    s0a = MFMA16(a0[2], bb[2], s0a); s0b = MFMA16(a0[3], bb[3], s0b);
    s1a = MFMA16(a1[2], bb[2], s1a); s1b = MFMA16(a1[3], bb[3], s1b);
    const int col = v * 16 + l16;
#pragma unroll
    for (int r = 0; r < 4; ++r) {
      float xv0 = X[(size_t)(R0 + quad * 4 + r) * DIM + col];      // L1/L2 hot
      float xv1 = X[(size_t)(R0 + 16 + quad * 4 + r) * DIM + col];
      y2 += (s0a[r] + s0b[r]) * xv0 + (s1a[r] + s1b[r]) * xv1;
    }
  }

  __syncthreads();  // drains vmcnt -> W fully staged; the ONLY barrier

  // ---- argmax: 32 W tiles, pure LDS + MFMA, no barriers ----
  float m0[4] = {0.f, 0.f, 0.f, 0.f}, m1[4] = {0.f, 0.f, 0.f, 0.f};
  float iv = cqb[l16];
  for (int t = 0; t < 32; ++t) {
    half8 bb[4];
#pragma unroll
    for (int ci = 0; ci < 4; ++ci)
      bb[ci] = *(const half8*)(Ws + moff(t * 16 + l16, ci * 32 + quad * 8));
    float ivn = (t < 31) ? cqb[(t + 1) * 16 + l16] : 0.f;  // prefetch next
    floatx4 s0a = {iv, iv, iv, iv}, s0b = {0.f, 0.f, 0.f, 0.f};
    floatx4 s1a = {iv, iv, iv, iv}, s1b = {0.f, 0.f, 0.f, 0.f};
    __builtin_amdgcn_s_setprio(1);
    s0a = MFMA16(a0[0], bb[0], s0a); s0b = MFMA16(a0[1], bb[1], s0b);
    s1a = MFMA16(a1[0], bb[0], s1a); s1b = MFMA16(a1[1], bb[1], s1b);
    s0a = MFMA16(a0[2], bb[2], s0a); s0b = MFMA16(a0[3], bb[3], s0b);
    s1a = MFMA16(a1[2], bb[2], s1a); s1b = MFMA16(a1[3], bb[3], s1b);
    __builtin_amdgcn_s_setprio(0);
    const unsigned tag = 511u - (unsigned)(t * 16 + l16);
#pragma unroll
    for (int r = 0; r < 4; ++r) {
      float v0 = s0a[r] + s0b[r], v1 = s1a[r] + s1b[r];
      unsigned u0 = ((__float_as_uint(v0) + 0x100u) & 0xFFFFFE00u) | tag;
      unsigned u1 = ((__float_as_uint(v1) + 0x100u) & 0xFFFFFE00u) | tag;
      m0[r] = fmaxf(m0[r], __uint_as_float(u0));
      m1[r] = fmaxf(m1[r], __uint_as_float(u1));
    }
    iv = ivn;
  }

  // cross-lane max over the 16 lanes sharing each row (packed: ties -> low idx)
#pragma unroll
  for (int r = 0; r < 4; ++r) {
#pragma unroll
    for (int msk = 1; msk < 16; msk <<= 1) {
      m0[r] = fmaxf(m0[r], __shfl_xor(m0[r], msk));
      m1[r] = fmaxf(m1[r], __shfl_xor(m1[r], msk));
    }
  }

  // ---- per-wave epilogue ----
  float contrib = y2;
  if (l16 == 0) {
#pragma unroll
    for (int r = 0; r < 4; ++r) {
      contrib -= 2.f * (__uint_as_float(__float_as_uint(m0[r]) & 0xFFFFFE00u) - 1024.f);
      contrib -= 2.f * (__uint_as_float(__float_as_uint(m1[r]) & 0xFFFFFE00u) - 1024.f);
    }
  }
#pragma unroll
  for (int msk = 1; msk < 64; msk <<= 1) contrib += __shfl_xor(contrib, msk);
  if (lane == 0) unsafeAtomicAdd(&sums[rep * 32], contrib);

  // gather quantized rows (codebook L2-resident) + idx store + histogram
  {
    const float4* cb4 = (const float4*)cb;
    float4* out4 = (float4*)out;
#pragma unroll
    for (int r = 0; r < 4; ++r) {
      const int j0 = 511 - (int)(__float_as_uint(m0[r]) & 511u);
      const int j1 = 511 - (int)(__float_as_uint(m1[r]) & 511u);
      const int row0 = R0 + quad * 4 + r, row1 = row0 + 16;
      out4[(size_t)row0 * 32 + l16 * 2]     = cb4[(size_t)j0 * 32 + l16 * 2];
      out4[(size_t)row0 * 32 + l16 * 2 + 1] = cb4[(size_t)j0 * 32 + l16 * 2 + 1];
      out4[(size_t)row1 * 32 + l16 * 2]     = cb4[(size_t)j1 * 32 + l16 * 2];
      out4[(size_t)row1 * 32 + l16 * 2 + 1] = cb4[(size_t)j1 * 32 + l16 * 2 + 1];
      if (l16 == 0) {
        out[ND + 2 + row0] = (float)j0;
        out[ND + 2 + row1] = (float)j1;
        atomicAdd(&cnt[rep * 512 + j0], 1u);
        atomicAdd(&cnt[rep * 512 + j1], 1u);
      }
    }
  }
}

// ---------------- finalize: entropy + losses ----------------
__global__ void k_final(const unsigned* __restrict__ cnt,
                        const float* __restrict__ sums, float* __restrict__ out) {
  __shared__ double sd[256];
  int t = threadIdx.x;
  double e = 0.0;
  for (int c = t; c < NCODE; c += 256) {
    unsigned u = 0;
#pragma unroll
    for (int r = 0; r < 8; ++r) u += cnt[r * 512 + c];
    float p = (float)u * (1.0f / 131072.0f);
    e += (double)(p * logf(p + 1e-8f));
  }
  sd[t] = e;
  __syncthreads();
  for (int k = 128; k > 0; k >>= 1) {
    if (t < k) sd[t] += sd[t + k];
    __syncthreads();
  }
  if (t == 0) {
    double ent = -sd[0];
    float st = 0.f;
#pragma unroll
    for (int r = 0; r < 8; ++r) st += sums[r * 32];
    double M = (double)st / 131072.0;
    out[ND] = (float)(0.1 * M);
    out[ND + 1] = (float)(M - 200000.0 * ent);
  }
}

// ---------------- launcher ----------------
extern "C" void kernel_launch(void* const* d_in, const int* in_sizes, int n_in,
                              void* d_out, int out_size, void* d_ws, size_t ws_size,
                              hipStream_t stream) {
  const float* X = (const float*)d_in[0];
  const float* cb = (const float*)d_in[1];
  char* ws = (char*)d_ws;
  _Float16* Lh = (_Float16*)(ws + WS_LH);
  _Float16* Ch = (_Float16*)(ws + WS_CH);
  _Float16* W = (_Float16*)(ws + WS_W);
  _Float16* Sh = (_Float16*)(ws + WS_SH);
  float* cqb = (float*)(ws + WS_CQ);
  unsigned* cnt = (unsigned*)(ws + WS_CNT);
  float* sums = (float*)(ws + WS_SUMS);
  float* out = (float*)d_out;

  k_prep1<<<64, 256, 0, stream>>>(cb, Lh, cnt, sums);
  k_prep23<<<40, 256, 0, stream>>>(cb, Lh, Ch, W, Sh, cqb);
  k_main<<<256, 1024, 0, stream>>>(X, cb, Sh, W, cqb, out, cnt, sums);
  k_final<<<1, 256, 0, stream>>>(cnt, sums, out);
}